// Round 7
// baseline (106.736 us; speedup 1.0000x reference)
//
#include <hip/hip_runtime.h>
#include <math.h>

// Chamfer distance, B=4, N=M=8192, D=3, fp32.
// Dot-product formulation: d^2/2 = 0.5|q|^2 + 0.5|r|^2 - q.r
// => min_r d^2  <=>  max_r t,  t = q.r - 0.5|r|^2.
// Inner loop: 3 fma + 0.5 v_max3 per pair = 3.5 VALU insts/pair.
// Floor: 537M pairs -> 1.88G lane-insts / (1024 SIMD-32 @ 2.4 GHz) ~ 24 us.
//
// Round-5 lesson: __launch_bounds__(256,8) made the allocator spill query
// state to scratch (VGPR 60 -> 28, inner-loop spill traffic, 45 us). Natural
// allocation is ~60 VGPR <= 64 => 8 waves/SIMD anyway. So: plain bounds.
// Round-4 lesson: keep 2048 blocks (MSPLIT=64) for co-residency.
// Round-3 lesson: NPT=8 keeps DS demand (16B/NPT per pair) under the VALU
// floor; broadcast float4 reads are conflict-free.
//
// Harness note: ~45 us of dur_us is the harness's 0xAA re-poison of the
// 256 MB ws buffer (fillBufferAligned in the profile) - not controllable.
//
// Direct path: each (query, slice) partial -> own ws slot [2B][64][NQ]
// (16 MB, all slots written; no sentinel memset, no atomics). NN kernel
// zeroes out[0] (stream-ordered before reduce). 2 graph nodes.
// Fallback (ws too small): proven sentinel/atomic 4-node path.

constexpr int TPB = 256;   // threads per block

template <int NPT, int MT, bool DIRECT>
__global__ __launch_bounds__(TPB) void chamfer_nn(
    const float* __restrict__ A,          // [B, N, 3] input cloud
    const float* __restrict__ Bp,         // [B, M, 3] target cloud
    float* __restrict__ wsD,              // [2B][gridDim.y][NQ] (DIRECT)
    unsigned int* __restrict__ minA,      // [B, N] sentinel path (!DIRECT)
    unsigned int* __restrict__ minB,      // [B, M] sentinel path (!DIRECT)
    int N, int M, int B, float* __restrict__ out)
{
    const int bz  = blockIdx.z;
    const int b   = bz % B;
    const int dir = bz / B;               // 0: query=A ref=B, 1: query=B ref=A

    if (DIRECT && bz == 0 && blockIdx.x == 0 && blockIdx.y == 0 &&
        threadIdx.x == 0) {
        *out = 0.0f;                      // reduce runs stream-after
    }

    const float* Q = dir ? Bp : A;
    const float* R = dir ? A  : Bp;
    const int NQ = dir ? M : N;
    const int NR = dir ? N : M;
    const int mSlice = NR / gridDim.y;

    const int tid    = threadIdx.x;
    const int nBase  = blockIdx.x * (TPB * NPT);
    const int mStart = blockIdx.y * mSlice;

    const float* qb = Q + (size_t)b * NQ * 3;
    const float* rb = R + (size_t)b * NR * 3;

    float qx[NPT], qy[NPT], qz[NPT], dmax[NPT];
#pragma unroll
    for (int k = 0; k < NPT; ++k) {
        const int n = nBase + tid + k * TPB;
        qx[k] = qb[n * 3 + 0];
        qy[k] = qb[n * 3 + 1];
        qz[k] = qb[n * 3 + 2];
        dmax[k] = -3.4e38f;
    }

    __shared__ float4 tgt[MT];  // {x, y, z, -0.5*|r|^2}

    for (int m0 = mStart; m0 < mStart + mSlice; m0 += MT) {
        __syncthreads();  // protect previous tile's readers
        if (tid < MT) {
            const float* src = rb + (size_t)(m0 + tid) * 3;
            const float rx = src[0];
            const float ry = src[1];
            const float rz = src[2];
            const float negc = -0.5f * fmaf(rz, rz, fmaf(ry, ry, rx * rx));
            tgt[tid] = make_float4(rx, ry, rz, negc);
        }
        __syncthreads();

#pragma unroll 2
        for (int j = 0; j < MT; j += 4) {
            // 4 refs = 4 broadcast ds_read_b128 (uniform addr -> conflict-
            // free), amortized over NPT queries: 16B/NPT DS bytes per pair.
            const float4 r0 = tgt[j + 0];
            const float4 r1 = tgt[j + 1];
            const float4 r2 = tgt[j + 2];
            const float4 r3 = tgt[j + 3];
#pragma unroll
            for (int k = 0; k < NPT; ++k) {
                const float t0 = fmaf(qz[k], r0.z, fmaf(qy[k], r0.y, fmaf(qx[k], r0.x, r0.w)));
                const float t1 = fmaf(qz[k], r1.z, fmaf(qy[k], r1.y, fmaf(qx[k], r1.x, r1.w)));
                const float t2 = fmaf(qz[k], r2.z, fmaf(qy[k], r2.y, fmaf(qx[k], r2.x, r2.w)));
                const float t3 = fmaf(qz[k], r3.z, fmaf(qy[k], r3.y, fmaf(qx[k], r3.x, r3.w)));
                // nested fmaxf pairs -> 2x v_max3_f32
                const float m01 = fmaxf(fmaxf(t0, t1), t2);
                dmax[k] = fmaxf(fmaxf(dmax[k], m01), t3);
            }
        }
    }

#pragma unroll
    for (int k = 0; k < NPT; ++k) {
        const int n = nBase + tid + k * TPB;
        // recompute 0.5|q|^2 here (epilogue) instead of carrying cq[NPT]
        // through the loop: -8 VGPRs of pressure, +3 insts/thread/k.
        const float c = 0.5f * fmaf(qz[k], qz[k], fmaf(qy[k], qy[k], qx[k] * qx[k]));
        const float sval = fmaxf(c - dmax[k], 0.0f);  // d^2/2, clamped
        if (DIRECT) {
            wsD[((size_t)bz * gridDim.y + blockIdx.y) * NQ + n] = sval;
        } else {
            // d2>=0 so f32 bit order == float order under uint min.
            unsigned int* om = dir ? minB : minA;
            atomicMin(&om[(size_t)b * NQ + n], __float_as_uint(sval));
        }
    }
}

// Direct-path reduce: min over S slices per query slot, then sqrt+mean+sum.
__global__ __launch_bounds__(256) void reduce_direct(
    const float* __restrict__ wsD, int NQ, int S, int B,
    float invN, float invM, float* __restrict__ out)
{
    const int total = 2 * B * NQ;
    float s = 0.0f;
    for (int i = blockIdx.x * blockDim.x + threadIdx.x; i < total;
         i += gridDim.x * blockDim.x) {
        const int bz = i / NQ;            // NQ is pow2 -> shifts
        const int n  = i - bz * NQ;
        const float* p = wsD + ((size_t)bz * S) * NQ + n;
        float v0 = p[0 * (size_t)NQ], v1 = p[1 * (size_t)NQ];
        float v2 = p[2 * (size_t)NQ], v3 = p[3 * (size_t)NQ];
        for (int sl = 4; sl < S; sl += 4) {
            v0 = fminf(v0, p[(size_t)(sl + 0) * NQ]);
            v1 = fminf(v1, p[(size_t)(sl + 1) * NQ]);
            v2 = fminf(v2, p[(size_t)(sl + 2) * NQ]);
            v3 = fminf(v3, p[(size_t)(sl + 3) * NQ]);
        }
        const float v = fminf(fminf(v0, v1), fminf(v2, v3));
        const float scale = (bz < B) ? invN : invM;
        s += sqrtf(2.0f * fmaxf(v, 0.0f)) * scale;
    }
#pragma unroll
    for (int off = 32; off > 0; off >>= 1) s += __shfl_down(s, off, 64);
    __shared__ float wsum[4];
    const int lane = threadIdx.x & 63;
    const int wid  = threadIdx.x >> 6;
    if (lane == 0) wsum[wid] = s;
    __syncthreads();
    if (threadIdx.x == 0) {
        atomicAdd(out, wsum[0] + wsum[1] + wsum[2] + wsum[3]);
    }
}

// Sentinel-path reduce (fallback).
__global__ __launch_bounds__(256) void chamfer_reduce(
    const unsigned int* __restrict__ mins, int nA, int nTotal,
    float scaleA, float scaleB, float* __restrict__ out)
{
    float s = 0.0f;
    for (int i = blockIdx.x * blockDim.x + threadIdx.x; i < nTotal;
         i += gridDim.x * blockDim.x) {
        const float half_d2 = __uint_as_float(mins[i]);
        s += sqrtf(2.0f * half_d2) * (i < nA ? scaleA : scaleB);
    }
#pragma unroll
    for (int off = 32; off > 0; off >>= 1) s += __shfl_down(s, off, 64);
    __shared__ float wsum[4];
    const int lane = threadIdx.x & 63;
    const int wid  = threadIdx.x >> 6;
    if (lane == 0) wsum[wid] = s;
    __syncthreads();
    if (threadIdx.x == 0) {
        atomicAdd(out, wsum[0] + wsum[1] + wsum[2] + wsum[3]);
    }
}

extern "C" void kernel_launch(void* const* d_in, const int* in_sizes, int n_in,
                              void* d_out, int out_size, void* d_ws, size_t ws_size,
                              hipStream_t stream) {
    const float* inp = (const float*)d_in[0];  // [B, N, 3]
    const float* tgt = (const float*)d_in[1];  // [B, M, 3]
    float* out = (float*)d_out;

    const int B = 4, D = 3;
    const int N = in_sizes[0] / (B * D);  // 8192
    const int M = in_sizes[1] / (B * D);  // 8192

    const int MSPLIT = 64;                       // slices (direct path)
    const size_t directNeed =
        (size_t)2 * B * MSPLIT * (size_t)N * sizeof(float);  // 16 MB

    if (N == M && (N % (TPB * 8)) == 0 && (N % MSPLIT) == 0 &&
        ws_size >= directNeed) {
        // ---- direct path: 2 graph nodes ----
        float* wsD = (float*)d_ws;
        dim3 grid(N / (TPB * 8), MSPLIT, 2 * B);   // (4, 64, 8) = 2048 blocks
        chamfer_nn<8, 128, true><<<grid, TPB, 0, stream>>>(
            inp, tgt, wsD, nullptr, nullptr, N, M, B, out);
        reduce_direct<<<dim3(256), 256, 0, stream>>>(
            wsD, N, MSPLIT, B, 1.0f / N, 1.0f / M, out);
    } else {
        // ---- fallback: proven sentinel/atomic path (4 nodes) ----
        unsigned int* min_in  = (unsigned int*)d_ws;
        unsigned int* min_tgt = min_in + (size_t)B * N;
        hipMemsetAsync(d_ws, 0xFF,
                       (size_t)(B * N + B * M) * sizeof(unsigned int), stream);
        hipMemsetAsync(d_out, 0, sizeof(float), stream);
        dim3 grid(N / (TPB * 4), 32, 2 * B);
        chamfer_nn<4, 256, false><<<grid, TPB, 0, stream>>>(
            inp, tgt, nullptr, min_in, min_tgt, N, M, B, out);
        chamfer_reduce<<<dim3(64), 256, 0, stream>>>(
            min_in, B * N, B * (N + M), 1.0f / N, 1.0f / M, out);
    }
}

// Round 9
// 88.158 us; speedup vs baseline: 1.2107x; 1.2107x over previous
//
#include <hip/hip_runtime.h>
#include <math.h>

// Chamfer distance, B=4, N=M=8192, D=3, fp32 — MFMA edition.
//
// t = q.r - c_r via v_mfma_f32_32x32x16_f16 with fp16 hi/lo split (fp32-
// exact to ~3e-6): x = hi + lo, K=16 packing:
//   A (ref, M-rows):  k0..7  = [h0,h1,h2,l0,l1,l2,h0,h1]
//                     k8..15 = [h2,-chi,-clo,0,0,0,0,0]
//   B (query, N-cols):k0..7  = [hq0,hq1,hq2,hq0,hq1,hq2,lq0,lq1]
//                     k8..15 = [lq2,1,1,0,0,0,0,0]
//   dot = (h+l).(hq+lq) - l.lq - c  (|l.lq| <= ~3e-6)
// min_r d^2/2 = cq - max_r t ; sqrt deferred to reduce.
//
// Fragment layouts (32x32x16): A row = lane&31, k = 8*(lane>>5)+e;
// B col = lane&31, same k. C (m74/m101-verified): col = lane&31,
// row = (reg&3)+8*(reg>>2)+4*(lane>>5) -> lanes l and l^32 cover
// complementary ref rows of the same query col: final shfl_xor(32)+max.
//
// prep kernel pre-packs ref fragments in exact wave-lane order so the NN
// kernel stages via global_load_lds(16B) and reads linear ds_read_b128
// (no swizzle anywhere; permutation lives in the global layout).
// C-input = persistent zero fragment (D != C is legal) -> no per-tile
// accumulator zeroing; per tile merge = 8 v_max3.
//
// Round-7 lesson: VALU path was at ~85-90% of the measured fp32 VALU issue
// ceiling (m07 ~3cyc/wave-inst) -> pipe change, not more squeezing.
// ~45 us of dur_us is the harness 0xAA re-poison of ws (uncontrollable).

typedef __attribute__((ext_vector_type(8)))  _Float16 f16x8;
typedef __attribute__((ext_vector_type(16))) float    f32x16;

constexpr int TPB    = 256;
constexpr int NPTS   = 8192;   // N == M
constexpr int NB     = 4;      // batch
constexpr int MSPLIT = 8;      // ref slices
constexpr int SLICE  = NPTS / MSPLIT;  // 1024 refs per block
constexpr int TILES  = SLICE / 32;     // 32 MFMA ref-tiles per block
constexpr int QPB    = 256;    // queries per block (4 waves x 64)

__device__ inline float max3f(float a, float b, float c) {
    return fmaxf(fmaxf(a, b), c);   // clang fuses to v_max3_f32
}

__device__ inline float merge16(float run, f32x16 v) {
    const float w0 = max3f(v[0],  v[1],  v[2]);
    const float w1 = max3f(v[3],  v[4],  v[5]);
    const float w2 = max3f(v[6],  v[7],  v[8]);
    const float w3 = max3f(v[9],  v[10], v[11]);
    const float w4 = max3f(v[12], v[13], v[14]);
    const float x0 = max3f(w0, w1, v[15]);
    const float x1 = max3f(w2, w3, w4);
    return max3f(run, x0, x1);
}

__device__ inline f16x8 make_qfrag(float x, float y, float z, int half) {
    const _Float16 hx = (_Float16)x, hy = (_Float16)y, hz = (_Float16)z;
    const _Float16 lx = (_Float16)(x - (float)hx);
    const _Float16 ly = (_Float16)(y - (float)hy);
    const _Float16 lz = (_Float16)(z - (float)hz);
    const f16x8 f0 = (f16x8){hx, hy, hz, hx, hy, hz, lx, ly};
    const f16x8 f1 = (f16x8){lz, (_Float16)1.0f, (_Float16)1.0f, 0, 0, 0, 0, 0};
    return half ? f1 : f0;
}

// ---- prep: pack ref fragments [cloudb(8)][tile(256)][half(2)][r(32)] 16B ----
__global__ __launch_bounds__(TPB) void prep_frags(
    const float* __restrict__ inp, const float* __restrict__ tgt,
    f16x8* __restrict__ frag, float* __restrict__ out)
{
    const int idx = blockIdx.x * TPB + threadIdx.x;  // 0..131071
    if (idx == 0) *out = 0.0f;                       // reduce runs stream-after
    const int rl    = idx & 31;
    const int half  = (idx >> 5) & 1;
    const int tile  = (idx >> 6) & 255;
    const int cb    = idx >> 14;       // cloud*4 + b
    const int cloud = cb >> 2;
    const int b     = cb & 3;
    const int r     = tile * 32 + rl;
    const float* src = (cloud ? tgt : inp) + ((size_t)b * NPTS + r) * 3;
    const float x = src[0], y = src[1], z = src[2];
    const _Float16 hx = (_Float16)x, hy = (_Float16)y, hz = (_Float16)z;
    const _Float16 lx = (_Float16)(x - (float)hx);
    const _Float16 ly = (_Float16)(y - (float)hy);
    const _Float16 lz = (_Float16)(z - (float)hz);
    const float c = 0.5f * (x * x + y * y + z * z);
    const _Float16 chi = (_Float16)c;
    const _Float16 clo = (_Float16)(c - (float)chi);
    const _Float16 nchi = -chi, nclo = -clo;
    f16x8 f;
    if (half == 0) f = (f16x8){hx, hy, hz, lx, ly, lz, hx, hy};
    else           f = (f16x8){hz, nchi, nclo, 0, 0, 0, 0, 0};
    frag[idx] = f;
}

// ---- NN: per wave 64 queries (2 MFMA N-tiles), scan 1024 refs ----
__global__ __launch_bounds__(TPB) void chamfer_nn_mfma(
    const float* __restrict__ inp, const float* __restrict__ tgt,
    const f16x8* __restrict__ frag, float* __restrict__ partial)
{
    const int z    = blockIdx.z;   // dir*4 + b
    const int dir  = z >> 2;
    const int b    = z & 3;
    const int s    = blockIdx.y;   // ref slice
    const int tid  = threadIdx.x;
    const int w    = tid >> 6;
    const int lane = tid & 63;
    const int half = lane >> 5;
    const int col  = lane & 31;

    __shared__ f16x8 lds[2048];    // 1024 refs x 2 halves x 16B = 32 KB

    {   // stage: pure copy, global pre-permuted to wave-lane order
        const int refcloud = dir ? 0 : 1;
        const f16x8* g = frag + ((size_t)(refcloud * 4 + b) * 16384
                                 + (size_t)s * (TILES * 64));
#pragma unroll
        for (int i = 0; i < 8; ++i) {
            __builtin_amdgcn_global_load_lds(
                (const void*)(g + i * 256 + w * 64 + lane),  // per-lane src
                (void*)&lds[i * 256 + w * 64],               // wave-uniform dst
                16, 0, 0);
        }
    }

    // queries: 2 column-tiles per wave
    const float* qb = (dir ? tgt : inp) + (size_t)b * NPTS * 3;
    const int qbase = blockIdx.x * QPB + w * 64;
    const int q0 = qbase + col, q1 = q0 + 32;
    const float x0 = qb[q0 * 3 + 0], y0 = qb[q0 * 3 + 1], z0 = qb[q0 * 3 + 2];
    const float x1 = qb[q1 * 3 + 0], y1 = qb[q1 * 3 + 1], z1 = qb[q1 * 3 + 2];
    const float cq0 = 0.5f * (x0 * x0 + y0 * y0 + z0 * z0);
    const float cq1 = 0.5f * (x1 * x1 + y1 * y1 + z1 * z1);
    const f16x8 bq0 = make_qfrag(x0, y0, z0, half);
    const f16x8 bq1 = make_qfrag(x1, y1, z1, half);

    __syncthreads();   // drains vmcnt for global_load_lds + barrier

    const f32x16 zf = (f32x16)0.0f;   // persistent zero C-operand
    float run0 = -3.4e38f, run1 = -3.4e38f;
#pragma unroll 4
    for (int t = 0; t < TILES; ++t) {
        const f16x8 a = lds[t * 64 + lane];   // linear ds_read_b128
        const f32x16 acc0 = __builtin_amdgcn_mfma_f32_32x32x16_f16(a, bq0, zf, 0, 0, 0);
        const f32x16 acc1 = __builtin_amdgcn_mfma_f32_32x32x16_f16(a, bq1, zf, 0, 0, 0);
        run0 = merge16(run0, acc0);
        run1 = merge16(run1, acc1);
    }

    // lanes l and l^32 hold complementary ref rows of the same query col
    run0 = fmaxf(run0, __shfl_xor(run0, 32));
    run1 = fmaxf(run1, __shfl_xor(run1, 32));

    if (lane < 32) {
        float* p = partial + ((size_t)z * MSPLIT + s) * NPTS;
        p[q0] = cq0 - run0;   // d^2/2 partial for this slice
        p[q1] = cq1 - run1;
    }
}

// ---- reduce: min over slices, sqrt, mean, sum ----
__global__ __launch_bounds__(256) void reduce_mfma(
    const float* __restrict__ partial, float* __restrict__ out, float inv)
{
    const int i = blockIdx.x * 256 + threadIdx.x;    // 65536 = 2*4*8192
    const float* p = partial + ((size_t)(i >> 13) * MSPLIT) * NPTS + (i & (NPTS - 1));
    float v = p[0];
#pragma unroll
    for (int sl = 1; sl < MSPLIT; ++sl) v = fminf(v, p[(size_t)sl * NPTS]);
    float sacc = sqrtf(fmaxf(2.0f * v, 0.0f)) * inv;
#pragma unroll
    for (int off = 32; off > 0; off >>= 1) sacc += __shfl_down(sacc, off, 64);
    __shared__ float wsum[4];
    const int lane = threadIdx.x & 63, wid = threadIdx.x >> 6;
    if (lane == 0) wsum[wid] = sacc;
    __syncthreads();
    if (threadIdx.x == 0) atomicAdd(out, wsum[0] + wsum[1] + wsum[2] + wsum[3]);
}

// ---- fallback (proven round-3 VALU path) ----
__global__ __launch_bounds__(TPB) void chamfer_nn_valu(
    const float* __restrict__ A, const float* __restrict__ Bp,
    unsigned int* __restrict__ minA, unsigned int* __restrict__ minB,
    int N, int M, int B)
{
    const int bz = blockIdx.z, b = bz % B, dir = bz / B;
    const float* Q = dir ? Bp : A;
    const float* R = dir ? A : Bp;
    unsigned int* om = dir ? minB : minA;
    const int NQ = dir ? M : N, NR = dir ? N : M;
    const int mSlice = NR / gridDim.y;
    const int tid = threadIdx.x;
    const int nBase = blockIdx.x * (TPB * 4);
    const int mStart = blockIdx.y * mSlice;
    const float* qb = Q + (size_t)b * NQ * 3;
    const float* rb = R + (size_t)b * NR * 3;
    float qx[4], qy[4], qz[4], dmax[4];
#pragma unroll
    for (int k = 0; k < 4; ++k) {
        const int n = nBase + tid + k * TPB;
        qx[k] = qb[n * 3]; qy[k] = qb[n * 3 + 1]; qz[k] = qb[n * 3 + 2];
        dmax[k] = -3.4e38f;
    }
    __shared__ float4 tgtl[256];
    for (int m0 = mStart; m0 < mStart + mSlice; m0 += 256) {
        __syncthreads();
        {
            const float* src = rb + (size_t)(m0 + tid) * 3;
            const float rx = src[0], ry = src[1], rz = src[2];
            tgtl[tid] = make_float4(rx, ry, rz,
                -0.5f * fmaf(rz, rz, fmaf(ry, ry, rx * rx)));
        }
        __syncthreads();
#pragma unroll 2
        for (int j = 0; j < 256; j += 2) {
            const float4 r0 = tgtl[j], r1 = tgtl[j + 1];
#pragma unroll
            for (int k = 0; k < 4; ++k) {
                const float t0 = fmaf(qz[k], r0.z, fmaf(qy[k], r0.y, fmaf(qx[k], r0.x, r0.w)));
                const float t1 = fmaf(qz[k], r1.z, fmaf(qy[k], r1.y, fmaf(qx[k], r1.x, r1.w)));
                dmax[k] = max3f(dmax[k], t0, t1);
            }
        }
    }
#pragma unroll
    for (int k = 0; k < 4; ++k) {
        const int n = nBase + tid + k * TPB;
        const float c = 0.5f * fmaf(qz[k], qz[k], fmaf(qy[k], qy[k], qx[k] * qx[k]));
        atomicMin(&om[(size_t)b * NQ + n], __float_as_uint(fmaxf(c - dmax[k], 0.0f)));
    }
}

__global__ __launch_bounds__(256) void chamfer_reduce(
    const unsigned int* __restrict__ mins, int nA, int nTotal,
    float scaleA, float scaleB, float* __restrict__ out)
{
    float s = 0.0f;
    for (int i = blockIdx.x * blockDim.x + threadIdx.x; i < nTotal;
         i += gridDim.x * blockDim.x) {
        s += sqrtf(2.0f * __uint_as_float(mins[i])) * (i < nA ? scaleA : scaleB);
    }
#pragma unroll
    for (int off = 32; off > 0; off >>= 1) s += __shfl_down(s, off, 64);
    __shared__ float wsum[4];
    const int lane = threadIdx.x & 63, wid = threadIdx.x >> 6;
    if (lane == 0) wsum[wid] = s;
    __syncthreads();
    if (threadIdx.x == 0) atomicAdd(out, wsum[0] + wsum[1] + wsum[2] + wsum[3]);
}

extern "C" void kernel_launch(void* const* d_in, const int* in_sizes, int n_in,
                              void* d_out, int out_size, void* d_ws, size_t ws_size,
                              hipStream_t stream) {
    const float* inp = (const float*)d_in[0];  // [B, N, 3]
    const float* tgt = (const float*)d_in[1];  // [B, M, 3]
    float* out = (float*)d_out;

    const int B = 4, D = 3;
    const int N = in_sizes[0] / (B * D);
    const int M = in_sizes[1] / (B * D);

    const size_t fragBytes    = (size_t)131072 * 16;            // 2 MB
    const size_t partialBytes = (size_t)8 * MSPLIT * NPTS * 4;  // 2 MB

    if (N == NPTS && M == NPTS && B == NB &&
        ws_size >= fragBytes + partialBytes) {
        f16x8* frag    = (f16x8*)d_ws;
        float* partial = (float*)((char*)d_ws + fragBytes);
        prep_frags<<<dim3(131072 / TPB), TPB, 0, stream>>>(inp, tgt, frag, out);
        dim3 grid(NPTS / QPB, MSPLIT, 8);   // (32, 8, 8) = 2048 blocks
        chamfer_nn_mfma<<<grid, TPB, 0, stream>>>(inp, tgt, frag, partial);
        reduce_mfma<<<dim3(65536 / 256), 256, 0, stream>>>(
            partial, out, 1.0f / NPTS);
    } else {
        // proven sentinel/atomic VALU path
        unsigned int* min_in  = (unsigned int*)d_ws;
        unsigned int* min_tgt = min_in + (size_t)B * N;
        hipMemsetAsync(d_ws, 0xFF,
                       (size_t)(B * N + B * M) * sizeof(unsigned int), stream);
        hipMemsetAsync(d_out, 0, sizeof(float), stream);
        dim3 grid(N / (TPB * 4), 32, 2 * B);
        chamfer_nn_valu<<<grid, TPB, 0, stream>>>(inp, tgt, min_in, min_tgt, N, M, B);
        chamfer_reduce<<<dim3(64), 256, 0, stream>>>(
            min_in, B * N, B * (N + M), 1.0f / N, 1.0f / M, out);
    }
}

// Round 10
// 75.881 us; speedup vs baseline: 1.4066x; 1.1618x over previous
//
#include <hip/hip_runtime.h>
#include <math.h>

// Chamfer distance, B=4, N=M=8192, D=3, fp32 — single fused MFMA kernel.
//
// t = q.r - c_r via v_mfma_f32_32x32x16_f16 with fp16 hi/lo split
// (HW-verified round 9, absmax 0.0):
//   A (ref):   k0..7  = [h0,h1,h2,l0,l1,l2,h0,h1]
//              k8..15 = [h2,-chi,-clo,0,0,0,0,0]
//   B (query): k0..7  = [hq0,hq1,hq2,hq0,hq1,hq2,lq0,lq1]
//              k8..15 = [lq2,1,1,0,0,0,0,0]
//   dot = (h+l).(hq+lq) - l.lq - c   (|l.lq| <= ~3e-6)
// min_r d^2/2 = cq - max_r t.
// A row = lane&31, k-half = lane>>5; C col = lane&31,
// row = (reg&3)+8*(reg>>2)+4*(lane>>5) -> shfl_xor(32)+max folds halves.
//
// Round-10 structure: MSPLIT=1 -> each block scans ALL refs for its 256
// queries, so the block holds FINAL mins -> sqrt+mean+atomicAdd locally.
// Kills prep kernel, frag buffer, partial buffer, reduce kernel: graph is
// memset(4B) + 1 kernel. Refs converted in-kernel and staged through
// double-buffered LDS (2 x 1024 refs x 32B = 64KB), one barrier per chunk;
// next chunk's global loads issue before the 32-tile MFMA loop (latency
// hidden under compute, compiler inserts the vmcnt at first use).
//
// ~41.5 us of dur_us is the harness 0xAA re-poison of the 256MB ws
// (fillBufferAligned) — uncontrollable floor; ws is UNUSED by fast path.

typedef __attribute__((ext_vector_type(8)))  _Float16 f16x8;
typedef __attribute__((ext_vector_type(16))) float    f32x16;

constexpr int TPB    = 512;            // 8 waves
constexpr int NPTS   = 8192;           // N == M
constexpr int NB     = 4;              // batch
constexpr int QPB    = 256;            // queries per block (8 waves x 32)
constexpr int CHUNK  = 1024;           // refs per LDS buffer
constexpr int NCHUNK = NPTS / CHUNK;   // 8
constexpr int TILES  = CHUNK / 32;     // 32 MFMA ref-tiles per chunk

__device__ inline float max3f(float a, float b, float c) {
    return fmaxf(fmaxf(a, b), c);   // clang fuses to v_max3_f32
}

__device__ inline float merge16(float run, f32x16 v) {
    const float w0 = max3f(v[0],  v[1],  v[2]);
    const float w1 = max3f(v[3],  v[4],  v[5]);
    const float w2 = max3f(v[6],  v[7],  v[8]);
    const float w3 = max3f(v[9],  v[10], v[11]);
    const float w4 = max3f(v[12], v[13], v[14]);
    const float x0 = max3f(w0, w1, v[15]);
    const float x1 = max3f(w2, w3, w4);
    return max3f(run, x0, x1);
}

__device__ inline f16x8 make_qfrag(float x, float y, float z, int half) {
    const _Float16 hx = (_Float16)x, hy = (_Float16)y, hz = (_Float16)z;
    const _Float16 lx = (_Float16)(x - (float)hx);
    const _Float16 ly = (_Float16)(y - (float)hy);
    const _Float16 lz = (_Float16)(z - (float)hz);
    const f16x8 f0 = (f16x8){hx, hy, hz, hx, hy, hz, lx, ly};
    const f16x8 f1 = (f16x8){lz, (_Float16)1.0f, (_Float16)1.0f, 0, 0, 0, 0, 0};
    return half ? f1 : f0;
}

// Convert one ref point and write both A-fragments at chunk-local index r.
// Write pattern (r = j*512 + tid): lanes 0..31 and 32..63 each hit a linear
// 512B LDS run -> conflict-free ds_write_b128.
__device__ inline void write_ref(f16x8* buf, int r, float x, float y, float z) {
    const _Float16 hx = (_Float16)x, hy = (_Float16)y, hz = (_Float16)z;
    const _Float16 lx = (_Float16)(x - (float)hx);
    const _Float16 ly = (_Float16)(y - (float)hy);
    const _Float16 lz = (_Float16)(z - (float)hz);
    const float c = 0.5f * fmaf(z, z, fmaf(y, y, x * x));
    const _Float16 chi = (_Float16)c;
    const _Float16 clo = (_Float16)(c - (float)chi);
    const int base = (r >> 5) * 64 + (r & 31);
    buf[base]      = (f16x8){hx, hy, hz, lx, ly, lz, hx, hy};
    buf[base + 32] = (f16x8){hz, -chi, -clo, 0, 0, 0, 0, 0};
}

__global__ __launch_bounds__(TPB) void chamfer_one(
    const float* __restrict__ inp, const float* __restrict__ tgt,
    float* __restrict__ out)
{
    const int dir = blockIdx.y >> 2;   // 0: query=inp ref=tgt; 1: swapped
    const int b   = blockIdx.y & 3;
    const float* qb = (dir ? tgt : inp) + (size_t)b * NPTS * 3;
    const float* rb = (dir ? inp : tgt) + (size_t)b * NPTS * 3;

    const int tid  = threadIdx.x;
    const int w    = tid >> 6;
    const int lane = tid & 63;
    const int half = lane >> 5;
    const int col  = lane & 31;

    // one query per lane-pair (lane, lane^32): 32 queries per wave
    const int q = blockIdx.x * QPB + w * 32 + col;
    const float qx = qb[q * 3 + 0], qy = qb[q * 3 + 1], qz = qb[q * 3 + 2];
    const f16x8 bq = make_qfrag(qx, qy, qz, half);

    __shared__ f16x8 lds[2 * 2048];    // 2 buffers x 1024 refs x 2 frags

    // prologue: stage chunk 0 into buffer 0
    {
        const float* s0 = rb + (size_t)tid * 3;
        const float* s1 = rb + (size_t)(512 + tid) * 3;
        write_ref(lds, tid,       s0[0], s0[1], s0[2]);
        write_ref(lds, 512 + tid, s1[0], s1[1], s1[2]);
    }
    __syncthreads();

    const f32x16 zf = (f32x16)0.0f;    // persistent zero C-operand
    float run = -3.4e38f;

    for (int c = 0; c < NCHUNK; ++c) {
        f16x8* bufR = lds + (c & 1) * 2048;
        f16x8* bufW = lds + ((c & 1) ^ 1) * 2048;

        // issue next chunk's loads early (compiler schedules them before
        // the MFMA loop; the waitcnt lands at first use after it)
        float nx0 = 0, ny0 = 0, nz0 = 0, nx1 = 0, ny1 = 0, nz1 = 0;
        const bool more = (c + 1 < NCHUNK);
        if (more) {
            const float* s0 = rb + (size_t)((c + 1) * CHUNK + tid) * 3;
            const float* s1 = rb + (size_t)((c + 1) * CHUNK + 512 + tid) * 3;
            nx0 = s0[0]; ny0 = s0[1]; nz0 = s0[2];
            nx1 = s1[0]; ny1 = s1[1]; nz1 = s1[2];
        }

#pragma unroll 4
        for (int t = 0; t < TILES; ++t) {
            const f16x8 a = bufR[t * 64 + lane];   // linear ds_read_b128
            const f32x16 acc =
                __builtin_amdgcn_mfma_f32_32x32x16_f16(a, bq, zf, 0, 0, 0);
            run = merge16(run, acc);
        }

        if (more) {
            write_ref(bufW, tid,       nx0, ny0, nz0);
            write_ref(bufW, 512 + tid, nx1, ny1, nz1);
        }
        __syncthreads();   // bufW visible; all waves done reading bufR
    }

    // fold the two k-halves (lanes l, l^32 hold complementary ref rows)
    run = fmaxf(run, __shfl_xor(run, 32));
    const float cq = 0.5f * fmaf(qz, qz, fmaf(qy, qy, qx * qx));
    const float sval = fmaxf(cq - run, 0.0f);          // final d^2/2
    float term = (lane < 32) ? sqrtf(2.0f * sval) * (1.0f / NPTS) : 0.0f;
#pragma unroll
    for (int off = 32; off > 0; off >>= 1) term += __shfl_down(term, off, 64);

    // block-sum via LDS (reuse staging memory; all compute is done)
    float* bs = (float*)lds;
    if (lane == 0) bs[w] = term;
    __syncthreads();
    if (tid == 0) {
        float s = 0.0f;
#pragma unroll
        for (int i = 0; i < 8; ++i) s += bs[i];
        atomicAdd(out, s);
    }
}

// ---- fallback (proven round-3 VALU path, general shapes) ----
__global__ __launch_bounds__(256) void chamfer_nn_valu(
    const float* __restrict__ A, const float* __restrict__ Bp,
    unsigned int* __restrict__ minA, unsigned int* __restrict__ minB,
    int N, int M, int B)
{
    const int bz = blockIdx.z, b = bz % B, dir = bz / B;
    const float* Q = dir ? Bp : A;
    const float* R = dir ? A : Bp;
    unsigned int* om = dir ? minB : minA;
    const int NQ = dir ? M : N, NR = dir ? N : M;
    const int mSlice = NR / gridDim.y;
    const int tid = threadIdx.x;
    const int nBase = blockIdx.x * (256 * 4);
    const int mStart = blockIdx.y * mSlice;
    const float* qb = Q + (size_t)b * NQ * 3;
    const float* rb = R + (size_t)b * NR * 3;
    float qx[4], qy[4], qz[4], dmax[4];
#pragma unroll
    for (int k = 0; k < 4; ++k) {
        const int n = nBase + tid + k * 256;
        qx[k] = qb[n * 3]; qy[k] = qb[n * 3 + 1]; qz[k] = qb[n * 3 + 2];
        dmax[k] = -3.4e38f;
    }
    __shared__ float4 tgtl[256];
    for (int m0 = mStart; m0 < mStart + mSlice; m0 += 256) {
        __syncthreads();
        {
            const float* src = rb + (size_t)(m0 + tid) * 3;
            const float rx = src[0], ry = src[1], rz = src[2];
            tgtl[tid] = make_float4(rx, ry, rz,
                -0.5f * fmaf(rz, rz, fmaf(ry, ry, rx * rx)));
        }
        __syncthreads();
#pragma unroll 2
        for (int j = 0; j < 256; j += 2) {
            const float4 r0 = tgtl[j], r1 = tgtl[j + 1];
#pragma unroll
            for (int k = 0; k < 4; ++k) {
                const float t0 = fmaf(qz[k], r0.z, fmaf(qy[k], r0.y, fmaf(qx[k], r0.x, r0.w)));
                const float t1 = fmaf(qz[k], r1.z, fmaf(qy[k], r1.y, fmaf(qx[k], r1.x, r1.w)));
                dmax[k] = max3f(dmax[k], t0, t1);
            }
        }
    }
#pragma unroll
    for (int k = 0; k < 4; ++k) {
        const int n = nBase + tid + k * 256;
        const float c = 0.5f * fmaf(qz[k], qz[k], fmaf(qy[k], qy[k], qx[k] * qx[k]));
        atomicMin(&om[(size_t)b * NQ + n], __float_as_uint(fmaxf(c - dmax[k], 0.0f)));
    }
}

__global__ __launch_bounds__(256) void chamfer_reduce(
    const unsigned int* __restrict__ mins, int nA, int nTotal,
    float scaleA, float scaleB, float* __restrict__ out)
{
    float s = 0.0f;
    for (int i = blockIdx.x * blockDim.x + threadIdx.x; i < nTotal;
         i += gridDim.x * blockDim.x) {
        s += sqrtf(2.0f * __uint_as_float(mins[i])) * (i < nA ? scaleA : scaleB);
    }
#pragma unroll
    for (int off = 32; off > 0; off >>= 1) s += __shfl_down(s, off, 64);
    __shared__ float wsum[4];
    const int lane = threadIdx.x & 63, wid = threadIdx.x >> 6;
    if (lane == 0) wsum[wid] = s;
    __syncthreads();
    if (threadIdx.x == 0) atomicAdd(out, wsum[0] + wsum[1] + wsum[2] + wsum[3]);
}

extern "C" void kernel_launch(void* const* d_in, const int* in_sizes, int n_in,
                              void* d_out, int out_size, void* d_ws, size_t ws_size,
                              hipStream_t stream) {
    const float* inp = (const float*)d_in[0];  // [B, N, 3]
    const float* tgt = (const float*)d_in[1];  // [B, M, 3]
    float* out = (float*)d_out;

    const int B = 4, D = 3;
    const int N = in_sizes[0] / (B * D);
    const int M = in_sizes[1] / (B * D);

    if (N == NPTS && M == NPTS && B == NB) {
        // ---- fused path: 2 graph nodes, ws unused ----
        hipMemsetAsync(d_out, 0, sizeof(float), stream);
        dim3 grid(NPTS / QPB, 2 * NB);          // (32, 8) = 256 blocks
        chamfer_one<<<grid, TPB, 0, stream>>>(inp, tgt, out);
    } else {
        // ---- fallback: proven sentinel/atomic VALU path ----
        unsigned int* min_in  = (unsigned int*)d_ws;
        unsigned int* min_tgt = min_in + (size_t)B * N;
        hipMemsetAsync(d_ws, 0xFF,
                       (size_t)(B * N + B * M) * sizeof(unsigned int), stream);
        hipMemsetAsync(d_out, 0, sizeof(float), stream);
        dim3 grid(N / (256 * 4), 32, 2 * B);
        chamfer_nn_valu<<<grid, 256, 0, stream>>>(inp, tgt, min_in, min_tgt, N, M, B);
        chamfer_reduce<<<dim3(64), 256, 0, stream>>>(
            min_in, B * N, B * (N + M), 1.0f / N, 1.0f / M, out);
    }
}